// Round 1
// baseline (594.975 us; speedup 1.0000x reference)
//
#include <hip/hip_runtime.h>
#include <math.h>

// MemoryCenters: sim = q·K^T (1024x100000, D=128), top-32 by rbf=exp(-2*dist_sq),
// softmax(log(rbf+eps)+log(h+eps)), r_V = w·V_sel, r_E = w·e_sel.
//
// Architecture (round 1): threshold-prepass so the heavy GEMM has a trivial epilogue.
//   pass1: fp32 GEMM q vs first 8192 centers -> sims in ws
//   thresh: per-query histogram -> conservative per-query threshold T_q (>=32 survivors guaranteed)
//   pass2: fp32 GEMM q vs all N, append (sim,idx) where sim >= T_q (atomic, ~400/query)
//   finalize: exact sorted top-32 (by rbf, tie -> lower index, matching jax.lax.top_k),
//             weights, V/e gathers, write all outputs.
// ws usage: 32MB sims + 8KB + 8MB candidates ~= 42MB.

#define DDIM    128
#define QT      128   // queries per block tile
#define TN      128   // centers per block tile
#define DC      64    // d-chunk staged in LDS
#define MSAMPLE 8192  // sample centers for threshold
#define NBINS   1024
#define CAP     1024  // candidate buffer per query
#define TOPK    32
#define NQTOT   1024  // B*T

// ---------------------------------------------------------------------------
// GEMM core. MODE 0: store sims for first MSAMPLE centers. MODE 1: threshold-append.
// LDS layout (per d-chunk, transposed): element (dcol, row) at word
//   dcol*128 + 4*(((row>>2) + (dcol>>2)) & 31) + (row&3)
// The quad rotation makes staging writes and frag reads <=2-way bank conflicts.
// ---------------------------------------------------------------------------
template<int MODE>
__global__ __launch_bounds__(256)
void gemm_pass(const float* __restrict__ Qg, const float* __restrict__ Kg,
               int N, int tileCount,
               float* __restrict__ simsOut,
               const float* __restrict__ thr,
               int* __restrict__ cnt, float* __restrict__ cval, int* __restrict__ cidx)
{
    __shared__ float Qs[DC * QT];   // 32 KB
    __shared__ float Ks[DC * TN];   // 32 KB
    const int tid = threadIdx.x;
    const int qg  = tid >> 4;       // 0..15 : query octet
    const int cg  = tid & 15;       // 0..15 : center group
    const int qbase = blockIdx.x * QT;

    float thrq[8];
    if (MODE == 1) {
        #pragma unroll
        for (int i = 0; i < 8; ++i) thrq[i] = thr[qbase + 8 * qg + i];
    }

    for (int t = blockIdx.y; t < tileCount; t += gridDim.y) {
        const int cbase = t * TN;
        float acc[8][8];
        #pragma unroll
        for (int i = 0; i < 8; ++i)
            #pragma unroll
            for (int j = 0; j < 8; ++j) acc[i][j] = 0.f;

        for (int d0 = 0; d0 < DDIM; d0 += DC) {
            __syncthreads();   // protect LDS reuse from previous chunk/tile reads
            // ---- stage Q chunk (128 rows x 64 dims), transposed+rotated ----
            #pragma unroll
            for (int it = 0; it < 8; ++it) {
                int i = it * 256 + tid;      // 0..2047
                int m = i & 15;              // d-quad within chunk
                int r = i >> 4;              // row 0..127
                float4 v = *reinterpret_cast<const float4*>(
                    &Qg[(size_t)(qbase + r) * DDIM + d0 + 4 * m]);
                int rq   = ((r >> 2) + m) & 31;
                int word = (4 * m) * QT + (rq << 2) + (r & 3);
                Qs[word         ] = v.x;
                Qs[word + QT    ] = v.y;
                Qs[word + 2*QT  ] = v.z;
                Qs[word + 3*QT  ] = v.w;
            }
            // ---- stage K chunk ----
            #pragma unroll
            for (int it = 0; it < 8; ++it) {
                int i = it * 256 + tid;
                int m = i & 15;
                int r = i >> 4;
                int row = cbase + r;
                float4 v = make_float4(0.f, 0.f, 0.f, 0.f);
                if (MODE == 0 || row < N)
                    v = *reinterpret_cast<const float4*>(
                        &Kg[(size_t)row * DDIM + d0 + 4 * m]);
                int rq   = ((r >> 2) + m) & 31;
                int word = (4 * m) * TN + (rq << 2) + (r & 3);
                Ks[word         ] = v.x;
                Ks[word + TN    ] = v.y;
                Ks[word + 2*TN  ] = v.z;
                Ks[word + 3*TN  ] = v.w;
            }
            __syncthreads();
            // ---- compute: 8q x 8c per thread ----
            #pragma unroll 8
            for (int d = 0; d < DC; ++d) {
                int rot = d >> 2;
                const float4 qa = *reinterpret_cast<const float4*>(
                    &Qs[d * QT + ((((qg << 1)     + rot) & 31) << 2)]);
                const float4 qb = *reinterpret_cast<const float4*>(
                    &Qs[d * QT + ((((qg << 1) + 1 + rot) & 31) << 2)]);
                const float4 ka = *reinterpret_cast<const float4*>(
                    &Ks[d * TN + (((cg        + rot) & 31) << 2)]);
                const float4 kb = *reinterpret_cast<const float4*>(
                    &Ks[d * TN + (((16 + cg   + rot) & 31) << 2)]);
                float qv[8] = {qa.x, qa.y, qa.z, qa.w, qb.x, qb.y, qb.z, qb.w};
                float kv[8] = {ka.x, ka.y, ka.z, ka.w, kb.x, kb.y, kb.z, kb.w};
                #pragma unroll
                for (int i = 0; i < 8; ++i)
                    #pragma unroll
                    for (int j = 0; j < 8; ++j)
                        acc[i][j] = fmaf(qv[i], kv[j], acc[i][j]);
            }
        }
        // ---- epilogue ----
        if (MODE == 0) {
            #pragma unroll
            for (int i = 0; i < 8; ++i) {
                int q = qbase + 8 * qg + i;
                #pragma unroll
                for (int j = 0; j < 8; ++j) {
                    int cl = (j < 4) ? (4 * cg + j) : (64 + 4 * cg + (j - 4));
                    simsOut[(size_t)q * MSAMPLE + cbase + cl] = acc[i][j];
                }
            }
        } else {
            #pragma unroll
            for (int i = 0; i < 8; ++i) {
                int q = qbase + 8 * qg + i;
                #pragma unroll
                for (int j = 0; j < 8; ++j) {
                    int cl = (j < 4) ? (4 * cg + j) : (64 + 4 * cg + (j - 4));
                    int c = cbase + cl;
                    float s = acc[i][j];
                    if (c < N && s >= thrq[i]) {
                        int p = atomicAdd(&cnt[q], 1);
                        if (p < CAP) {
                            cval[(size_t)q * CAP + p] = s;
                            cidx[(size_t)q * CAP + p] = c;
                        }
                    }
                }
            }
        }
    }
}

// ---------------------------------------------------------------------------
// Per-query threshold from sample sims: histogram + suffix-sum; T = lower edge of
// (bin holding 32nd-largest) minus one full bin (completeness margin vs fp rounding).
// ---------------------------------------------------------------------------
__global__ __launch_bounds__(256)
void thresh_kernel(const float* __restrict__ sims, float* __restrict__ thr)
{
    __shared__ int hA[NBINS];
    __shared__ int hB[NBINS];
    __shared__ int best;
    const int q = blockIdx.x, tid = threadIdx.x;
    for (int i = tid; i < NBINS; i += 256) hA[i] = 0;
    if (tid == 0) best = 0;
    __syncthreads();
    for (int i = tid; i < MSAMPLE; i += 256) {
        float s = sims[(size_t)q * MSAMPLE + i];
        int b = (int)((s + 1.0f) * (NBINS * 0.5f));
        b = b < 0 ? 0 : (b > NBINS - 1 ? NBINS - 1 : b);
        atomicAdd(&hA[b], 1);
    }
    __syncthreads();
    int* src = hA; int* dst = hB;
    for (int off = 1; off < NBINS; off <<= 1) {
        for (int i = tid; i < NBINS; i += 256)
            dst[i] = src[i] + ((i + off < NBINS) ? src[i + off] : 0);
        __syncthreads();
        int* tmp = src; src = dst; dst = tmp;
    }
    for (int i = tid; i < NBINS; i += 256)
        if (src[i] >= TOPK) atomicMax(&best, i);
    __syncthreads();
    if (tid == 0)
        thr[q] = (float)(best - 1) * (2.0f / NBINS) - 1.0f;
}

// ---------------------------------------------------------------------------
// Finalize: exact sorted top-32 by rbf (tie -> lower center index, = jax.lax.top_k),
// softmax weights per reference formula, V/e gathers, write all 4 outputs.
// ---------------------------------------------------------------------------
__global__ __launch_bounds__(256)
void finalize_kernel(const float* __restrict__ cval, const int* __restrict__ cidx,
                     const int* __restrict__ cnt,
                     const float* __restrict__ V, const float* __restrict__ hIn,
                     const float* __restrict__ eIn,
                     float* __restrict__ out, int N)
{
    __shared__ float rv[CAP];
    __shared__ int   ri[CAP];
    __shared__ float selV[TOPK];
    __shared__ int   selI[TOPK];
    __shared__ float wts[TOPK];
    const int q = blockIdx.x, tid = threadIdx.x;
    const int n = min(cnt[q], CAP);
    for (int i = tid; i < CAP; i += 256) {
        if (i < n) {
            float s    = cval[(size_t)q * CAP + i];
            float dist = 2.0f - 2.0f * s;           // matches reference ops exactly
            rv[i] = expf(dist * -2.0f);             // exp(-dist_sq/(2*0.25))
            ri[i] = cidx[(size_t)q * CAP + i];
        } else {
            rv[i] = -1.0f;                          // below any rbf (>0)
            ri[i] = 0x7fffffff;
        }
    }
    __syncthreads();
    // wave 0 does 32 rounds of argmax (value desc, tie -> lower index)
    if (tid < 64) {
        for (int r = 0; r < TOPK; ++r) {
            float bv = -1.0f; int bi = 0x7fffffff; int bp = -1;
            for (int i = tid; i < CAP; i += 64) {
                float v = rv[i]; int ix = ri[i];
                if (v > bv || (v == bv && ix < bi)) { bv = v; bi = ix; bp = i; }
            }
            #pragma unroll
            for (int o = 32; o > 0; o >>= 1) {
                float ov = __shfl_down(bv, o);
                int   oi = __shfl_down(bi, o);
                int   op = __shfl_down(bp, o);
                if (ov > bv || (ov == bv && oi < bi)) { bv = ov; bi = oi; bp = op; }
            }
            bp = __shfl(bp, 0);                     // broadcast winner position
            if (tid == 0) { selV[r] = bv; selI[r] = bi; }
            // only lane (bp&63) ever reads slot bp again -> same-thread ordering is safe
            if ((bp & 63) == tid) rv[bp] = -1.0f;
        }
    }
    __syncthreads();
    if (tid < TOPK) {
        float lw = logf(selV[tid] + 1e-8f) + logf(hIn[selI[tid]] + 1e-8f);
        float mx = lw;
        #pragma unroll
        for (int o = 16; o > 0; o >>= 1) mx = fmaxf(mx, __shfl_xor(mx, o));
        float ex = expf(lw - mx);
        float sm = ex;
        #pragma unroll
        for (int o = 16; o > 0; o >>= 1) sm += __shfl_xor(sm, o);
        wts[tid] = ex / sm;
    }
    __syncthreads();
    // r_V : thread v owns one of 256 output dims
    {
        float acc = 0.f;
        const int v = tid;
        #pragma unroll 8
        for (int k = 0; k < TOPK; ++k)
            acc = fmaf(wts[k], V[(size_t)selI[k] * 256 + v], acc);
        out[(size_t)q * 256 + v] = acc;
    }
    const int offE = NQTOT * 256;
    const int offW = offE + NQTOT * 4;
    const int offI = offW + NQTOT * TOPK;
    if (tid < 4) {
        float acc = 0.f;
        for (int k = 0; k < TOPK; ++k)
            acc = fmaf(wts[k], eIn[(size_t)selI[k] * 4 + tid], acc);
        out[offE + q * 4 + tid] = acc;
    }
    if (tid < TOPK) {
        out[offW + q * TOPK + tid] = wts[tid];
        out[offI + q * TOPK + tid] = (float)selI[tid];   // int32 index as float
    }
}

// ---------------------------------------------------------------------------
extern "C" void kernel_launch(void* const* d_in, const int* in_sizes, int n_in,
                              void* d_out, int out_size, void* d_ws, size_t ws_size,
                              hipStream_t stream)
{
    (void)n_in; (void)out_size; (void)ws_size;
    const float* Qg = (const float*)d_in[0];
    const float* Kg = (const float*)d_in[1];
    const float* Vg = (const float*)d_in[2];
    const float* hg = (const float*)d_in[3];
    const float* eg = (const float*)d_in[4];
    const int N = in_sizes[1] / DDIM;          // 100000

    char* w = (char*)d_ws;
    float* sims = (float*)w;  w += (size_t)NQTOT * MSAMPLE * 4;   // 32 MB
    float* thr  = (float*)w;  w += NQTOT * 4;
    int*   cnt  = (int*)w;    w += NQTOT * 4;
    float* cval = (float*)w;  w += (size_t)NQTOT * CAP * 4;       // 4 MB
    int*   cidx = (int*)w;                                        // 4 MB

    hipMemsetAsync(cnt, 0, NQTOT * 4, stream);

    dim3 blk(256);
    gemm_pass<0><<<dim3(NQTOT / QT, 16), blk, 0, stream>>>(
        Qg, Kg, N, MSAMPLE / TN, sims, nullptr, nullptr, nullptr, nullptr);
    thresh_kernel<<<dim3(NQTOT), blk, 0, stream>>>(sims, thr);
    const int tiles = (N + TN - 1) / TN;       // 782
    gemm_pass<1><<<dim3(NQTOT / QT, 64), blk, 0, stream>>>(
        Qg, Kg, N, tiles, nullptr, thr, cnt, cval, cidx);
    finalize_kernel<<<dim3(NQTOT), blk, 0, stream>>>(
        cval, cidx, cnt, Vg, hg, eg, (float*)d_out, N);
}